// Round 5
// baseline (1319.981 us; speedup 1.0000x reference)
//
#include <hip/hip_runtime.h>
#include <stdint.h>

// MinGRUBlock on MI355X (gfx950). Input/output dtype (f32 vs bf16) is DETECTED
// at runtime from x's bit patterns (flag in ws); all raw-input reads and the
// final d_out writes branch on it. Internals are bf16 (weights converted into
// ws once). Residual x_cur lives in ws. GEMMs: mfma_f32_16x16x32_bf16, 128x128
// tile, BK=64, global_load_lds w=16, B staged [N][K]. Scan: 3-phase chunked,
// h_t = sigmoid(-g)*h + sigmoid(g)*gfun(hid), f32 carry across segments.

#define DM     1024
#define SEQL   4096
#define FFN    2730
#define FFP    2816
#define NH_OFF 16777216L
#define CHLEN  128

using bf16x8 = __attribute__((ext_vector_type(8))) short;
using f32x4  = __attribute__((ext_vector_type(4))) float;

__device__ __forceinline__ float bf2f(unsigned short h) {
  union { unsigned int u; float f; } v; v.u = ((unsigned int)h) << 16; return v.f;
}
__device__ __forceinline__ unsigned short f2bf(float f) {
  union { float f; unsigned int u; } v; v.f = f;
  unsigned int u = v.u;
  return (unsigned short)((u + 0x7fffu + ((u >> 16) & 1u)) >> 16);
}
__device__ __forceinline__ float ldin(const void* p, long i, int f32mode) {
  return f32mode ? ((const float*)p)[i] : bf2f(((const unsigned short*)p)[i]);
}
__device__ __forceinline__ void stout(void* p, long i, int f32mode, float v) {
  if (f32mode) ((float*)p)[i] = v; else ((unsigned short*)p)[i] = f2bf(v);
}
__device__ __forceinline__ void gload_lds16(const unsigned short* g, unsigned short* lds) {
  __builtin_amdgcn_global_load_lds(
      (const __attribute__((address_space(1))) unsigned int*)g,
      (__attribute__((address_space(3))) unsigned int*)lds,
      16, 0, 0);
}

// ---------------- dtype detection --------------------------------------------
// Even-index u16s of a true-bf16 N(0,1) buffer have exponent <= ~0x81.
// If the buffer is f32, even u16s are low mantissa bits (uniform) -> ~48% have
// exponent >= 0x84. Count over 1024 even u16s; >=32 hits -> f32.
__global__ void detect_k(const unsigned short* __restrict__ x, int* __restrict__ flag) {
  __shared__ int cnt;
  if (threadIdx.x == 0) cnt = 0;
  __syncthreads();
  int c = 0;
  for (int j = 0; j < 4; j++) {
    unsigned short v = x[2 * (threadIdx.x * 4 + j)];
    int ex = (v >> 7) & 0xFF;
    if (ex >= 0x84) c++;
  }
  atomicAdd(&cnt, c);
  __syncthreads();
  if (threadIdx.x == 0) *flag = (cnt >= 32) ? 1 : 0;
}

// ---------------- GEMM: C[M,N] = A[M,K] * B^T  (B stored [N][K], ldb=K) -------
// EPI 0: bf16 plain. EPI 1: bf16 = acc + bias[col] + raw_res (flag). 
// EPI 2: bf16 = acc + bf16res. EPI 3: raw_out (flag) = acc + bf16res.
template <int EPI>
__launch_bounds__(256)
__global__ void gemm_bf16(const unsigned short* __restrict__ A, int lda, int aOffZ,
                          const unsigned short* __restrict__ Bm, int bOffZ, int K,
                          void* __restrict__ Cout, int ldc, int cOffZ, long outOff,
                          const unsigned short* __restrict__ bias,
                          const void* __restrict__ res, int ldres, long resOff,
                          const int* __restrict__ flagp) {
  __shared__ __align__(16) unsigned short As[128][64];
  __shared__ __align__(16) unsigned short Bs[128][64];

  const int tid  = threadIdx.x;
  const int w    = tid >> 6;
  const int lane = tid & 63;
  const int z    = blockIdx.z;
  const long tm  = (long)blockIdx.y * 128;
  const long tn  = (long)blockIdx.x * 128;

  const unsigned short* Ag = A + (long)z * aOffZ;
  const unsigned short* Bg = Bm + (long)z * bOffZ;

  f32x4 acc[4][4];
#pragma unroll
  for (int i = 0; i < 4; i++)
#pragma unroll
    for (int j = 0; j < 4; j++) acc[i][j] = (f32x4){0.f, 0.f, 0.f, 0.f};

  const int wrow = w * 32;
  const int srow = lane >> 3;
  const int scol = (lane & 7) * 8;
  const int wm   = (w >> 1) * 64;
  const int wn   = (w & 1) * 64;
  const int quad = lane >> 4;
  const int lo   = lane & 15;

  for (int k0 = 0; k0 < K; k0 += 64) {
    __syncthreads();
#pragma unroll
    for (int i = 0; i < 4; i++) {
      const int r = wrow + i * 8;  // wave-uniform LDS base
      gload_lds16(Ag + (tm + r + srow) * (long)lda + k0 + scol, &As[r][0]);
      gload_lds16(Bg + (tn + r + srow) * (long)K + k0 + scol, &Bs[r][0]);
    }
    __syncthreads();
#pragma unroll
    for (int kk = 0; kk < 64; kk += 32) {
      bf16x8 af[4], bfr[4];
#pragma unroll
      for (int mt = 0; mt < 4; mt++)
        af[mt] = *(const bf16x8*)&As[wm + mt * 16 + lo][kk + quad * 8];
#pragma unroll
      for (int nt = 0; nt < 4; nt++)
        bfr[nt] = *(const bf16x8*)&Bs[wn + nt * 16 + lo][kk + quad * 8];
#pragma unroll
      for (int mt = 0; mt < 4; mt++)
#pragma unroll
        for (int nt = 0; nt < 4; nt++)
          acc[mt][nt] = __builtin_amdgcn_mfma_f32_16x16x32_bf16(af[mt], bfr[nt], acc[mt][nt], 0, 0, 0);
    }
  }

  const int f32m = (EPI == 1 || EPI == 3) ? *flagp : 0;
#pragma unroll
  for (int mt = 0; mt < 4; mt++) {
#pragma unroll
    for (int nt = 0; nt < 4; nt++) {
#pragma unroll
      for (int r = 0; r < 4; r++) {
        const long grow = tm + wm + mt * 16 + quad * 4 + r;
        const long gcol = tn + wn + nt * 16 + lo;
        float v         = acc[mt][nt][r];
        if (EPI == 0) {
          ((unsigned short*)Cout + (long)z * cOffZ)[grow * (long)ldc + gcol] = f2bf(v);
        } else if (EPI == 1) {
          v += bf2f(bias[gcol]) + ldin(res, resOff + grow * (long)ldres + gcol, f32m);
          ((unsigned short*)Cout)[grow * (long)ldc + gcol] = f2bf(v);
        } else if (EPI == 2) {
          v += bf2f(((const unsigned short*)res + (long)z * cOffZ)[grow * (long)ldres + gcol]);
          ((unsigned short*)Cout + (long)z * cOffZ)[grow * (long)ldc + gcol] = f2bf(v);
        } else {  // EPI == 3: final output
          v += bf2f(((const unsigned short*)res)[grow * (long)ldres + gcol]);
          stout(Cout, outOff + grow * (long)ldc + gcol, f32m, v);
        }
      }
    }
  }
}

// ---------------- fused FF GEMM: ffin = silu(A@Wg^T) * (A@Wv^T) --------------
__launch_bounds__(256)
__global__ void gemm_ff(const unsigned short* __restrict__ A,
                        const unsigned short* __restrict__ Bgm,
                        const unsigned short* __restrict__ Bvm,
                        unsigned short* __restrict__ Cout) {
  __shared__ __align__(16) unsigned short As[128][64];
  __shared__ __align__(16) unsigned short Bgs[128][64];
  __shared__ __align__(16) unsigned short Bvs[128][64];

  const int tid  = threadIdx.x;
  const int w    = tid >> 6;
  const int lane = tid & 63;
  const long tm  = (long)blockIdx.y * 128;
  const long tn  = (long)blockIdx.x * 128;

  f32x4 accG[4][4], accV[4][4];
#pragma unroll
  for (int i = 0; i < 4; i++)
#pragma unroll
    for (int j = 0; j < 4; j++) {
      accG[i][j] = (f32x4){0.f, 0.f, 0.f, 0.f};
      accV[i][j] = (f32x4){0.f, 0.f, 0.f, 0.f};
    }

  const int wrow = w * 32;
  const int srow = lane >> 3;
  const int scol = (lane & 7) * 8;
  const int wm   = (w >> 1) * 64;
  const int wn   = (w & 1) * 64;
  const int quad = lane >> 4;
  const int lo   = lane & 15;

  for (int k0 = 0; k0 < DM; k0 += 64) {
    __syncthreads();
#pragma unroll
    for (int i = 0; i < 4; i++) {
      const int r = wrow + i * 8;
      gload_lds16(A + (tm + r + srow) * (long)DM + k0 + scol, &As[r][0]);
      gload_lds16(Bgm + (tn + r + srow) * (long)DM + k0 + scol, &Bgs[r][0]);
      gload_lds16(Bvm + (tn + r + srow) * (long)DM + k0 + scol, &Bvs[r][0]);
    }
    __syncthreads();
#pragma unroll
    for (int kk = 0; kk < 64; kk += 32) {
      bf16x8 af[4], bfr[4];
#pragma unroll
      for (int mt = 0; mt < 4; mt++)
        af[mt] = *(const bf16x8*)&As[wm + mt * 16 + lo][kk + quad * 8];
#pragma unroll
      for (int nt = 0; nt < 4; nt++)
        bfr[nt] = *(const bf16x8*)&Bgs[wn + nt * 16 + lo][kk + quad * 8];
#pragma unroll
      for (int mt = 0; mt < 4; mt++)
#pragma unroll
        for (int nt = 0; nt < 4; nt++)
          accG[mt][nt] = __builtin_amdgcn_mfma_f32_16x16x32_bf16(af[mt], bfr[nt], accG[mt][nt], 0, 0, 0);
#pragma unroll
      for (int nt = 0; nt < 4; nt++)
        bfr[nt] = *(const bf16x8*)&Bvs[wn + nt * 16 + lo][kk + quad * 8];
#pragma unroll
      for (int mt = 0; mt < 4; mt++)
#pragma unroll
        for (int nt = 0; nt < 4; nt++)
          accV[mt][nt] = __builtin_amdgcn_mfma_f32_16x16x32_bf16(af[mt], bfr[nt], accV[mt][nt], 0, 0, 0);
    }
  }

#pragma unroll
  for (int mt = 0; mt < 4; mt++) {
#pragma unroll
    for (int nt = 0; nt < 4; nt++) {
#pragma unroll
      for (int r = 0; r < 4; r++) {
        const long grow = tm + wm + mt * 16 + quad * 4 + r;
        const long gcol = tn + wn + nt * 16 + lo;
        const float g   = accG[mt][nt][r];
        const float s   = g / (1.f + __expf(-g));
        Cout[grow * (long)FFP + gcol] = f2bf(s * accV[mt][nt][r]);
      }
    }
  }
}

// ---------------- RMSNorm: raw input variant (flag) --------------------------
__global__ void rmsnorm_x(const void* __restrict__ in, long elemOff,
                          const unsigned short* __restrict__ gamma,
                          unsigned short* __restrict__ out,
                          const int* __restrict__ flagp) {
  const int t    = blockIdx.x;
  const int lane = threadIdx.x;
  const int f32m = *flagp;
  float v[16];
  const long base = elemOff + (long)t * DM;
  if (f32m) {
    const float4* rp = (const float4*)((const float*)in + base);
#pragma unroll
    for (int j = 0; j < 4; j++) {
      float4 u     = rp[j * 64 + lane];
      v[j * 4 + 0] = u.x; v[j * 4 + 1] = u.y; v[j * 4 + 2] = u.z; v[j * 4 + 3] = u.w;
    }
  } else {
    const ushort4* rp = (const ushort4*)((const unsigned short*)in + base);
#pragma unroll
    for (int j = 0; j < 4; j++) {
      ushort4 u    = rp[j * 64 + lane];
      v[j * 4 + 0] = bf2f(u.x); v[j * 4 + 1] = bf2f(u.y);
      v[j * 4 + 2] = bf2f(u.z); v[j * 4 + 3] = bf2f(u.w);
    }
  }
  float s = 0.f;
#pragma unroll
  for (int i = 0; i < 16; i++) s = fmaf(v[i], v[i], s);
#pragma unroll
  for (int off = 32; off > 0; off >>= 1) s += __shfl_xor(s, off, 64);
  const float scale = 32.f / fmaxf(sqrtf(s), 1e-12f);
  ushort4* op       = (ushort4*)(out + (long)t * DM);
  const ushort4* gp = (const ushort4*)gamma;
#pragma unroll
  for (int j = 0; j < 4; j++) {
    ushort4 g = gp[j * 64 + lane];
    ushort4 o;
    o.x = f2bf(v[j * 4 + 0] * scale * (bf2f(g.x) + 1.f));
    o.y = f2bf(v[j * 4 + 1] * scale * (bf2f(g.y) + 1.f));
    o.z = f2bf(v[j * 4 + 2] * scale * (bf2f(g.z) + 1.f));
    o.w = f2bf(v[j * 4 + 3] * scale * (bf2f(g.w) + 1.f));
    op[j * 64 + lane] = o;
  }
}

// ---------------- RMSNorm (bf16 in/out) --------------------------------------
__global__ void rmsnorm_k(const unsigned short* __restrict__ in,
                          const unsigned short* __restrict__ gamma,
                          unsigned short* __restrict__ out) {
  const int t    = blockIdx.x;
  const int lane = threadIdx.x;
  float v[16];
  const ushort4* rp = (const ushort4*)(in + (long)t * DM);
#pragma unroll
  for (int j = 0; j < 4; j++) {
    ushort4 u    = rp[j * 64 + lane];
    v[j * 4 + 0] = bf2f(u.x); v[j * 4 + 1] = bf2f(u.y);
    v[j * 4 + 2] = bf2f(u.z); v[j * 4 + 3] = bf2f(u.w);
  }
  float s = 0.f;
#pragma unroll
  for (int i = 0; i < 16; i++) s = fmaf(v[i], v[i], s);
#pragma unroll
  for (int off = 32; off > 0; off >>= 1) s += __shfl_xor(s, off, 64);
  const float scale = 32.f / fmaxf(sqrtf(s), 1e-12f);
  ushort4* op       = (ushort4*)(out + (long)t * DM);
  const ushort4* gp = (const ushort4*)gamma;
#pragma unroll
  for (int j = 0; j < 4; j++) {
    ushort4 g = gp[j * 64 + lane];
    ushort4 o;
    o.x = f2bf(v[j * 4 + 0] * scale * (bf2f(g.x) + 1.f));
    o.y = f2bf(v[j * 4 + 1] * scale * (bf2f(g.y) + 1.f));
    o.z = f2bf(v[j * 4 + 2] * scale * (bf2f(g.z) + 1.f));
    o.w = f2bf(v[j * 4 + 3] * scale * (bf2f(g.w) + 1.f));
    op[j * 64 + lane] = o;
  }
}

// ---------------- causal depthwise conv K=4 ----------------------------------
__global__ void dwconv_k(const unsigned short* __restrict__ xn,
                         const unsigned short* __restrict__ dww,
                         const unsigned short* __restrict__ dwb,
                         unsigned short* __restrict__ y, int l0) {
  const int t = blockIdx.x;
  const int d = blockIdx.y * 256 + threadIdx.x;
  const int l = l0 + (t & (SEQL - 1));
  ushort4 w4  = ((const ushort4*)dww)[d];
  float wk[4] = {bf2f(w4.x), bf2f(w4.y), bf2f(w4.z), bf2f(w4.w)};
  float acc   = bf2f(dwb[d]);
#pragma unroll
  for (int k = 0; k < 4; k++) {
    const int ll = l + k - 3;
    if (ll >= 0) acc = fmaf(bf2f(xn[(long)(t + k - 3) * DM + d]), wk[k], acc);
  }
  y[(long)t * DM + d] = f2bf(acc);
}

// ---------------- scan --------------------------------------------------------
__device__ __forceinline__ void cv_compute(float gt, float& c, float& sg) {
  gt = fminf(fmaxf(gt, -40.f), 40.f);
  const float e  = __expf(-fabsf(gt));
  const float r  = 1.f / (1.f + e);
  const float rs = e * r;
  c  = (gt >= 0.f) ? rs : r;   // sigmoid(-gt)
  sg = (gt >= 0.f) ? r : rs;   // sigmoid(gt)
}
__device__ __forceinline__ float gfun(float hid) {
  hid = fminf(fmaxf(hid, -40.f), 40.f);
  if (hid >= 0.f) return hid + 0.5f;
  const float e = __expf(hid);
  return e / (1.f + e);
}

__global__ void scan_p1(const unsigned short* __restrict__ hg, float* __restrict__ cC,
                        float* __restrict__ cV, int chTot, int SL) {
  const int e = threadIdx.x, bh = blockIdx.y, cid = blockIdx.x;
  const int bL = bh >> 2, hh = bh & 3;
  long base = ((long)(bL * SL + cid * CHLEN)) * 3072 + hh * 768 + e;
  float C = 1.f, V = 0.f;
  for (int i = 0; i < CHLEN; i++) {
    const float hid = bf2f(hg[base]), gt = bf2f(hg[base + 384]);
    float c, sg; cv_compute(gt, c, sg);
    C *= c;
    V = fmaf(c, V, sg * gfun(hid));
    base += 3072;
  }
  const int idx = cid * chTot + bh * 384 + e;
  cC[idx] = C; cV[idx] = V;
}

__global__ void scan_p2(const float* __restrict__ cC, const float* __restrict__ cV,
                        float* __restrict__ hin, int chTot, int CHNp,
                        const float* __restrict__ hcarry, int useCarry) {
  const int ch = blockIdx.x * 384 + threadIdx.x;
  float h = useCarry ? hcarry[ch] : 0.f;
  for (int cid = 0; cid < CHNp; cid++) {
    const int idx = cid * chTot + ch;
    hin[idx] = h;
    h = fmaf(cC[idx], h, cV[idx]);
  }
}

__global__ void scan_p3(const unsigned short* __restrict__ hg, const float* __restrict__ hin,
                        unsigned short* __restrict__ hout, void* __restrict__ nh, long nhOff,
                        float* __restrict__ hcarry, int chTot, int SL, int CHNp,
                        int writeNh, const int* __restrict__ flagp) {
  const int e = threadIdx.x, bh = blockIdx.y, cid = blockIdx.x;
  const int bL = bh >> 2, hh = bh & 3;
  const long tok = (long)bL * SL + (long)cid * CHLEN;
  long base  = tok * 3072 + hh * 768 + e;
  long obase = tok * 1536 + hh * 384 + e;
  float h = hin[cid * chTot + bh * 384 + e];
  for (int i = 0; i < CHLEN; i++) {
    const float hid = bf2f(hg[base]), gt = bf2f(hg[base + 384]);
    float c, sg; cv_compute(gt, c, sg);
    h = fmaf(c, h, sg * gfun(hid));
    hout[obase] = f2bf(h);
    base += 3072; obase += 1536;
  }
  if (cid == CHNp - 1) {
    hcarry[bh * 384 + e] = h;
    if (writeNh) stout(nh, nhOff + bL * 1536 + hh * 384 + e, *flagp, h);
  }
}

// ---------------- weight conversion / transposes (flag-branching reads) -------
__global__ void cvt_k(const void* __restrict__ in, unsigned short* __restrict__ out,
                      int n, const int* __restrict__ flagp) {
  const int i = blockIdx.x * 256 + threadIdx.x;
  if (i < n) out[i] = f2bf(ldin(in, i, *flagp));
}
__global__ void tr_whg(const void* __restrict__ in, unsigned short* __restrict__ out,
                       const int* __restrict__ flagp) {
  const int idx = blockIdx.x * 256 + threadIdx.x;  // (h*768+n)*256+k
  const int k = idx & 255, n = (idx >> 8) % 768, h = idx / (768 * 256);
  out[idx] = f2bf(ldin(in, (long)(h * 256 + k) * 768 + n, *flagp));
}
__global__ void tr_wout(const void* __restrict__ in, unsigned short* __restrict__ out,
                        const int* __restrict__ flagp) {
  const int idx = blockIdx.x * 256 + threadIdx.x;  // (h*256+n)*384+k
  const int k = idx % 384, n = (idx / 384) & 255, h = idx / (384 * 256);
  out[idx] = f2bf(ldin(in, (long)(h * 384 + k) * 256 + n, *flagp));
}
__global__ void tr_wg(const void* __restrict__ in, unsigned short* __restrict__ out,
                      const int* __restrict__ flagp) {
  const int idx = blockIdx.x * 256 + threadIdx.x;  // n*1024+k, n<2816
  const int k = idx & 1023, n = idx >> 10;
  out[idx] = (n < FFN) ? f2bf(ldin(in, (long)k * FFN + n, *flagp)) : (unsigned short)0;
}
__global__ void tr_wfo(const void* __restrict__ in, unsigned short* __restrict__ out,
                       const int* __restrict__ flagp) {
  const int idx = blockIdx.x * 256 + threadIdx.x;  // n*2816+kk
  const int kk = idx % FFP, n = idx / FFP;
  out[idx] = (kk < FFN) ? f2bf(ldin(in, (long)kk * DM + n, *flagp)) : (unsigned short)0;
}

// ---------------- launch ------------------------------------------------------
extern "C" void kernel_launch(void* const* d_in, const int* in_sizes, int n_in,
                              void* d_out, int out_size, void* d_ws, size_t ws_size,
                              hipStream_t stream) {
  const void* x      = d_in[0];
  const void* dw_w   = d_in[1];
  const void* dw_b   = d_in[2];
  const void* pw_w   = d_in[3];  // [N=1024][K=1024] already
  const void* pw_b   = d_in[4];
  const void* conv_g = d_in[5];
  const void* gru_g  = d_in[6];
  const void* ff_g   = d_in[7];
  const void* w_hg   = d_in[8];
  const void* w_out  = d_in[9];
  const void* w_gate = d_in[10];
  const void* w_val  = d_in[11];
  const void* w_ffo  = d_in[12];

  // Pass size from ws_size (deterministic): need(MT) = 21,795,072 + MT*13,888.
  const long FIXED = 21795072L;
  int MT = 128;
  if      (ws_size >= (size_t)(FIXED + 8192L * 13888)) MT = 8192;
  else if (ws_size >= (size_t)(FIXED + 4096L * 13888)) MT = 4096;
  else if (ws_size >= (size_t)(FIXED + 2048L * 13888)) MT = 2048;
  else if (ws_size >= (size_t)(FIXED + 1024L * 13888)) MT = 1024;
  else if (ws_size >= (size_t)(FIXED + 512L * 13888))  MT = 512;
  else if (ws_size >= (size_t)(FIXED + 256L * 13888))  MT = 256;

  const int SL    = (MT >= SEQL) ? SEQL : MT;
  const int nSeq  = MT / SL;
  const int CHNp  = SL / CHLEN;
  const int chTot = nSeq * 1536;

  char* p = (char*)d_ws;
  unsigned short* whgT  = (unsigned short*)p; p += 1572864;
  unsigned short* woutT = (unsigned short*)p; p += 786432;
  unsigned short* wgT   = (unsigned short*)p; p += 5767168;
  unsigned short* wvT   = (unsigned short*)p; p += 5767168;
  unsigned short* wfoT  = (unsigned short*)p; p += 5767168;
  unsigned short* pwT   = (unsigned short*)p; p += 2097152;
  unsigned short* dwwB  = (unsigned short*)p; p += 8192;
  unsigned short* dwbB  = (unsigned short*)p; p += 2048;
  unsigned short* pwbB  = (unsigned short*)p; p += 2048;
  unsigned short* cgB   = (unsigned short*)p; p += 2048;
  unsigned short* ggB   = (unsigned short*)p; p += 2048;
  unsigned short* fgB   = (unsigned short*)p; p += 2048;
  int*            flag  = (int*)p;            p += 256;
  float*          hcarry= (float*)p;          p += 12288;
  float*          cC    = (float*)p;          p += (long)MT * 192;
  float*          cV    = (float*)p;          p += (long)MT * 192;
  float*          hin   = (float*)p;          p += (long)MT * 192;
  unsigned short* xnb   = (unsigned short*)p; p += 6144 + (long)MT * 2048;
  unsigned short* xc    = (unsigned short*)p; p += (long)MT * 2048;
  unsigned short* hbuf  = (unsigned short*)p; p += (long)MT * 3072;
  unsigned short* ybuf  = (unsigned short*)p;  // region R: ybuf / hg / ffin
  unsigned short* hg    = (unsigned short*)p;
  unsigned short* ffin  = (unsigned short*)p;
  unsigned short* xn    = xnb + 3 * DM;

  // dtype detection + weight conversion (once per call)
  detect_k<<<1, 256, 0, stream>>>((const unsigned short*)x, flag);
  tr_whg<<<3072, 256, 0, stream>>>(w_hg, whgT, flag);
  tr_wout<<<1536, 256, 0, stream>>>(w_out, woutT, flag);
  tr_wg<<<11264, 256, 0, stream>>>(w_gate, wgT, flag);
  tr_wg<<<11264, 256, 0, stream>>>(w_val, wvT, flag);
  tr_wfo<<<11264, 256, 0, stream>>>(w_ffo, wfoT, flag);
  cvt_k<<<4096, 256, 0, stream>>>(pw_w, pwT, 1048576, flag);
  cvt_k<<<16, 256, 0, stream>>>(dw_w, dwwB, 4096, flag);
  cvt_k<<<4, 256, 0, stream>>>(dw_b, dwbB, 1024, flag);
  cvt_k<<<4, 256, 0, stream>>>(pw_b, pwbB, 1024, flag);
  cvt_k<<<4, 256, 0, stream>>>(conv_g, cgB, 1024, flag);
  cvt_k<<<4, 256, 0, stream>>>(gru_g, ggB, 1024, flag);
  cvt_k<<<4, 256, 0, stream>>>(ff_g, fgB, 1024, flag);

  for (long t0 = 0; t0 < 16384; t0 += MT) {
    const int l0     = (int)(t0 & (SEQL - 1));
    const int P      = (l0 > 0) ? 3 : 0;
    const int seqEnd = (l0 + SL == SEQL);
    const long nhOff = NH_OFF + (t0 / SEQL) * 1536;

    // conv block: xc = pw(dwconv(rmsnorm(x))) + pw_b + x
    rmsnorm_x<<<MT + P, 64, 0, stream>>>(x, (t0 - P) * DM, cgB, xn - (long)P * DM, flag);
    dwconv_k<<<dim3(MT, 4), 256, 0, stream>>>(xn, dwwB, dwbB, ybuf, l0);
    gemm_bf16<1><<<dim3(8, MT / 128, 1), 256, 0, stream>>>(ybuf, DM, 0, pwT, 0, DM,
        xc, DM, 0, 0L, pwbB, x, DM, t0 * DM, flag);

    // GRU block
    rmsnorm_k<<<MT, 64, 0, stream>>>(xc, ggB, xn);
    gemm_bf16<0><<<dim3(6, MT / 128, 4), 256, 0, stream>>>(xn, DM, 256, whgT, 196608, 256,
        hg, 3072, 768, 0L, nullptr, nullptr, 0, 0L, nullptr);
    scan_p1<<<dim3(CHNp, nSeq * 4), 384, 0, stream>>>(hg, cC, cV, chTot, SL);
    scan_p2<<<nSeq * 4, 384, 0, stream>>>(cC, cV, hin, chTot, CHNp, hcarry, l0 > 0);
    scan_p3<<<dim3(CHNp, nSeq * 4), 384, 0, stream>>>(hg, hin, hbuf, d_out, nhOff,
        hcarry, chTot, SL, CHNp, seqEnd, flag);
    gemm_bf16<2><<<dim3(2, MT / 128, 4), 256, 0, stream>>>(hbuf, 1536, 384, woutT, 98304, 384,
        xc, DM, 256, 0L, nullptr, xc, DM, 0L, nullptr);

    // FF block
    rmsnorm_k<<<MT, 64, 0, stream>>>(xc, fgB, xn);
    gemm_ff<<<dim3(22, MT / 128), 256, 0, stream>>>(xn, wgT, wvT, ffin);
    gemm_bf16<3><<<dim3(8, MT / 128, 1), 256, 0, stream>>>(ffin, FFP, 0, wfoT, 0, FFP,
        d_out, DM, 0, t0 * DM, nullptr, xc, DM, 0L, flag);
  }
}

// Round 6
// 1122.344 us; speedup vs baseline: 1.1761x; 1.1761x over previous
//
#include <hip/hip_runtime.h>
#include <stdint.h>

// MinGRUBlock on MI355X (gfx950). Input/output dtype (f32 vs bf16) DETECTED at
// runtime from x's bit patterns (flag in ws). Internals bf16. Residual in ws.
// GEMMs: mfma_f32_16x16x32_bf16, 128x128 tile, BK=64, global_load_lds w=16,
// XOR-swizzled LDS tiles (chunk c of row r at c^(r&7)) to kill bank conflicts.
// Scan: 3-phase chunked, h_t = sigmoid(-g)*h + sigmoid(g)*gfun(hid), f32 carry.

#define DM     1024
#define SEQL   4096
#define FFN    2730
#define FFP    2816
#define NH_OFF 16777216L
#define CHLEN  128

using bf16x8 = __attribute__((ext_vector_type(8))) short;
using f32x4  = __attribute__((ext_vector_type(4))) float;

__device__ __forceinline__ float bf2f(unsigned short h) {
  union { unsigned int u; float f; } v; v.u = ((unsigned int)h) << 16; return v.f;
}
__device__ __forceinline__ unsigned short f2bf(float f) {
  union { float f; unsigned int u; } v; v.f = f;
  unsigned int u = v.u;
  return (unsigned short)((u + 0x7fffu + ((u >> 16) & 1u)) >> 16);
}
__device__ __forceinline__ float ldin(const void* p, long i, int f32mode) {
  return f32mode ? ((const float*)p)[i] : bf2f(((const unsigned short*)p)[i]);
}
__device__ __forceinline__ void stout(void* p, long i, int f32mode, float v) {
  if (f32mode) ((float*)p)[i] = v; else ((unsigned short*)p)[i] = f2bf(v);
}
__device__ __forceinline__ void gload_lds16(const unsigned short* g, unsigned short* lds) {
  __builtin_amdgcn_global_load_lds(
      (const __attribute__((address_space(1))) unsigned int*)g,
      (__attribute__((address_space(3))) unsigned int*)lds,
      16, 0, 0);
}

// ---------------- dtype detection --------------------------------------------
__global__ void detect_k(const unsigned short* __restrict__ x, int* __restrict__ flag) {
  __shared__ int cnt;
  if (threadIdx.x == 0) cnt = 0;
  __syncthreads();
  int c = 0;
  for (int j = 0; j < 4; j++) {
    unsigned short v = x[2 * (threadIdx.x * 4 + j)];
    int ex = (v >> 7) & 0xFF;
    if (ex >= 0x84) c++;
  }
  atomicAdd(&cnt, c);
  __syncthreads();
  if (threadIdx.x == 0) *flag = (cnt >= 32) ? 1 : 0;
}

// ---------------- GEMM: C[M,N] = A[M,K] * B^T  (B stored [N][K], ldb=K) -------
// EPI 0: bf16 plain. EPI 1: bf16 = acc + bias[col] + raw_res (flag).
// EPI 2: bf16 = acc + bf16res. EPI 3: raw_out (flag) = acc + bf16res.
template <int EPI>
__launch_bounds__(256)
__global__ void gemm_bf16(const unsigned short* __restrict__ A, int lda, int aOffZ,
                          const unsigned short* __restrict__ Bm, int bOffZ, int K,
                          void* __restrict__ Cout, int ldc, int cOffZ, long outOff,
                          const unsigned short* __restrict__ bias,
                          const void* __restrict__ res, int ldres, long resOff,
                          const int* __restrict__ flagp) {
  __shared__ __align__(16) unsigned short As[128][64];
  __shared__ __align__(16) unsigned short Bs[128][64];

  const int tid  = threadIdx.x;
  const int w    = tid >> 6;
  const int lane = tid & 63;
  const int z    = blockIdx.z;
  const long tm  = (long)blockIdx.y * 128;
  const long tn  = (long)blockIdx.x * 128;

  const unsigned short* Ag = A + (long)z * aOffZ;
  const unsigned short* Bg = Bm + (long)z * bOffZ;

  f32x4 acc[4][4];
#pragma unroll
  for (int i = 0; i < 4; i++)
#pragma unroll
    for (int j = 0; j < 4; j++) acc[i][j] = (f32x4){0.f, 0.f, 0.f, 0.f};

  const int wrow = w * 32;
  const int srow = lane >> 3;                    // 0..7
  const int scol = (((lane & 7) ^ srow) * 8);    // xor-swizzled source chunk
  const int wm   = (w >> 1) * 64;
  const int wn   = (w & 1) * 64;
  const int quad = lane >> 4;
  const int lo   = lane & 15;
  const int sw   = lo & 7;                       // row-based xor key for reads

  for (int k0 = 0; k0 < K; k0 += 64) {
    __syncthreads();
#pragma unroll
    for (int i = 0; i < 4; i++) {
      const int r = wrow + i * 8;  // wave-uniform LDS base
      gload_lds16(Ag + (tm + r + srow) * (long)lda + k0 + scol, &As[r][0]);
      gload_lds16(Bg + (tn + r + srow) * (long)K + k0 + scol, &Bs[r][0]);
    }
    __syncthreads();
#pragma unroll
    for (int kk = 0; kk < 64; kk += 32) {
      const int kc = kk >> 3;  // 0 or 4
      bf16x8 af[4], bfr[4];
#pragma unroll
      for (int mt = 0; mt < 4; mt++)
        af[mt] = *(const bf16x8*)&As[wm + mt * 16 + lo][((quad + kc) ^ sw) * 8];
#pragma unroll
      for (int nt = 0; nt < 4; nt++)
        bfr[nt] = *(const bf16x8*)&Bs[wn + nt * 16 + lo][((quad + kc) ^ sw) * 8];
#pragma unroll
      for (int mt = 0; mt < 4; mt++)
#pragma unroll
        for (int nt = 0; nt < 4; nt++)
          acc[mt][nt] = __builtin_amdgcn_mfma_f32_16x16x32_bf16(af[mt], bfr[nt], acc[mt][nt], 0, 0, 0);
    }
  }

  const int f32m = (EPI == 1 || EPI == 3) ? *flagp : 0;
#pragma unroll
  for (int mt = 0; mt < 4; mt++) {
#pragma unroll
    for (int nt = 0; nt < 4; nt++) {
#pragma unroll
      for (int r = 0; r < 4; r++) {
        const long grow = tm + wm + mt * 16 + quad * 4 + r;
        const long gcol = tn + wn + nt * 16 + lo;
        float v         = acc[mt][nt][r];
        if (EPI == 0) {
          ((unsigned short*)Cout + (long)z * cOffZ)[grow * (long)ldc + gcol] = f2bf(v);
        } else if (EPI == 1) {
          v += bf2f(bias[gcol]) + ldin(res, resOff + grow * (long)ldres + gcol, f32m);
          ((unsigned short*)Cout)[grow * (long)ldc + gcol] = f2bf(v);
        } else if (EPI == 2) {
          v += bf2f(((const unsigned short*)res + (long)z * cOffZ)[grow * (long)ldres + gcol]);
          ((unsigned short*)Cout + (long)z * cOffZ)[grow * (long)ldc + gcol] = f2bf(v);
        } else {  // EPI == 3: final output
          v += bf2f(((const unsigned short*)res)[grow * (long)ldres + gcol]);
          stout(Cout, outOff + grow * (long)ldc + gcol, f32m, v);
        }
      }
    }
  }
}

// ---------------- fused FF GEMM: ffin = silu(A@Wg^T) * (A@Wv^T) --------------
__launch_bounds__(256)
__global__ void gemm_ff(const unsigned short* __restrict__ A,
                        const unsigned short* __restrict__ Bgm,
                        const unsigned short* __restrict__ Bvm,
                        unsigned short* __restrict__ Cout) {
  __shared__ __align__(16) unsigned short As[128][64];
  __shared__ __align__(16) unsigned short Bgs[128][64];
  __shared__ __align__(16) unsigned short Bvs[128][64];

  const int tid  = threadIdx.x;
  const int w    = tid >> 6;
  const int lane = tid & 63;
  const long tm  = (long)blockIdx.y * 128;
  const long tn  = (long)blockIdx.x * 128;

  f32x4 accG[4][4], accV[4][4];
#pragma unroll
  for (int i = 0; i < 4; i++)
#pragma unroll
    for (int j = 0; j < 4; j++) {
      accG[i][j] = (f32x4){0.f, 0.f, 0.f, 0.f};
      accV[i][j] = (f32x4){0.f, 0.f, 0.f, 0.f};
    }

  const int wrow = w * 32;
  const int srow = lane >> 3;
  const int scol = (((lane & 7) ^ srow) * 8);
  const int wm   = (w >> 1) * 64;
  const int wn   = (w & 1) * 64;
  const int quad = lane >> 4;
  const int lo   = lane & 15;
  const int sw   = lo & 7;

  for (int k0 = 0; k0 < DM; k0 += 64) {
    __syncthreads();
#pragma unroll
    for (int i = 0; i < 4; i++) {
      const int r = wrow + i * 8;
      gload_lds16(A + (tm + r + srow) * (long)DM + k0 + scol, &As[r][0]);
      gload_lds16(Bgm + (tn + r + srow) * (long)DM + k0 + scol, &Bgs[r][0]);
      gload_lds16(Bvm + (tn + r + srow) * (long)DM + k0 + scol, &Bvs[r][0]);
    }
    __syncthreads();
#pragma unroll
    for (int kk = 0; kk < 64; kk += 32) {
      const int kc = kk >> 3;
      bf16x8 af[4], bfr[4];
#pragma unroll
      for (int mt = 0; mt < 4; mt++)
        af[mt] = *(const bf16x8*)&As[wm + mt * 16 + lo][((quad + kc) ^ sw) * 8];
#pragma unroll
      for (int nt = 0; nt < 4; nt++)
        bfr[nt] = *(const bf16x8*)&Bgs[wn + nt * 16 + lo][((quad + kc) ^ sw) * 8];
#pragma unroll
      for (int mt = 0; mt < 4; mt++)
#pragma unroll
        for (int nt = 0; nt < 4; nt++)
          accG[mt][nt] = __builtin_amdgcn_mfma_f32_16x16x32_bf16(af[mt], bfr[nt], accG[mt][nt], 0, 0, 0);
#pragma unroll
      for (int nt = 0; nt < 4; nt++)
        bfr[nt] = *(const bf16x8*)&Bvs[wn + nt * 16 + lo][((quad + kc) ^ sw) * 8];
#pragma unroll
      for (int mt = 0; mt < 4; mt++)
#pragma unroll
        for (int nt = 0; nt < 4; nt++)
          accV[mt][nt] = __builtin_amdgcn_mfma_f32_16x16x32_bf16(af[mt], bfr[nt], accV[mt][nt], 0, 0, 0);
    }
  }

#pragma unroll
  for (int mt = 0; mt < 4; mt++) {
#pragma unroll
    for (int nt = 0; nt < 4; nt++) {
#pragma unroll
      for (int r = 0; r < 4; r++) {
        const long grow = tm + wm + mt * 16 + quad * 4 + r;
        const long gcol = tn + wn + nt * 16 + lo;
        const float g   = accG[mt][nt][r];
        const float s   = g / (1.f + __expf(-g));
        Cout[grow * (long)FFP + gcol] = f2bf(s * accV[mt][nt][r]);
      }
    }
  }
}

// ---------------- RMSNorm: raw input variant (flag) --------------------------
__global__ void rmsnorm_x(const void* __restrict__ in, long elemOff,
                          const unsigned short* __restrict__ gamma,
                          unsigned short* __restrict__ out,
                          const int* __restrict__ flagp) {
  const int t    = blockIdx.x;
  const int lane = threadIdx.x;
  const int f32m = *flagp;
  float v[16];
  const long base = elemOff + (long)t * DM;
  if (f32m) {
    const float4* rp = (const float4*)((const float*)in + base);
#pragma unroll
    for (int j = 0; j < 4; j++) {
      float4 u     = rp[j * 64 + lane];
      v[j * 4 + 0] = u.x; v[j * 4 + 1] = u.y; v[j * 4 + 2] = u.z; v[j * 4 + 3] = u.w;
    }
  } else {
    const ushort4* rp = (const ushort4*)((const unsigned short*)in + base);
#pragma unroll
    for (int j = 0; j < 4; j++) {
      ushort4 u    = rp[j * 64 + lane];
      v[j * 4 + 0] = bf2f(u.x); v[j * 4 + 1] = bf2f(u.y);
      v[j * 4 + 2] = bf2f(u.z); v[j * 4 + 3] = bf2f(u.w);
    }
  }
  float s = 0.f;
#pragma unroll
  for (int i = 0; i < 16; i++) s = fmaf(v[i], v[i], s);
#pragma unroll
  for (int off = 32; off > 0; off >>= 1) s += __shfl_xor(s, off, 64);
  const float scale = 32.f / fmaxf(sqrtf(s), 1e-12f);
  ushort4* op       = (ushort4*)(out + (long)t * DM);
  const ushort4* gp = (const ushort4*)gamma;
#pragma unroll
  for (int j = 0; j < 4; j++) {
    ushort4 g = gp[j * 64 + lane];
    ushort4 o;
    o.x = f2bf(v[j * 4 + 0] * scale * (bf2f(g.x) + 1.f));
    o.y = f2bf(v[j * 4 + 1] * scale * (bf2f(g.y) + 1.f));
    o.z = f2bf(v[j * 4 + 2] * scale * (bf2f(g.z) + 1.f));
    o.w = f2bf(v[j * 4 + 3] * scale * (bf2f(g.w) + 1.f));
    op[j * 64 + lane] = o;
  }
}

// ---------------- RMSNorm (bf16 in/out) --------------------------------------
__global__ void rmsnorm_k(const unsigned short* __restrict__ in,
                          const unsigned short* __restrict__ gamma,
                          unsigned short* __restrict__ out) {
  const int t    = blockIdx.x;
  const int lane = threadIdx.x;
  float v[16];
  const ushort4* rp = (const ushort4*)(in + (long)t * DM);
#pragma unroll
  for (int j = 0; j < 4; j++) {
    ushort4 u    = rp[j * 64 + lane];
    v[j * 4 + 0] = bf2f(u.x); v[j * 4 + 1] = bf2f(u.y);
    v[j * 4 + 2] = bf2f(u.z); v[j * 4 + 3] = bf2f(u.w);
  }
  float s = 0.f;
#pragma unroll
  for (int i = 0; i < 16; i++) s = fmaf(v[i], v[i], s);
#pragma unroll
  for (int off = 32; off > 0; off >>= 1) s += __shfl_xor(s, off, 64);
  const float scale = 32.f / fmaxf(sqrtf(s), 1e-12f);
  ushort4* op       = (ushort4*)(out + (long)t * DM);
  const ushort4* gp = (const ushort4*)gamma;
#pragma unroll
  for (int j = 0; j < 4; j++) {
    ushort4 g = gp[j * 64 + lane];
    ushort4 o;
    o.x = f2bf(v[j * 4 + 0] * scale * (bf2f(g.x) + 1.f));
    o.y = f2bf(v[j * 4 + 1] * scale * (bf2f(g.y) + 1.f));
    o.z = f2bf(v[j * 4 + 2] * scale * (bf2f(g.z) + 1.f));
    o.w = f2bf(v[j * 4 + 3] * scale * (bf2f(g.w) + 1.f));
    op[j * 64 + lane] = o;
  }
}

// ---------------- causal depthwise conv K=4 ----------------------------------
__global__ void dwconv_k(const unsigned short* __restrict__ xn,
                         const unsigned short* __restrict__ dww,
                         const unsigned short* __restrict__ dwb,
                         unsigned short* __restrict__ y, int l0) {
  const int t = blockIdx.x;
  const int d = blockIdx.y * 256 + threadIdx.x;
  const int l = l0 + (t & (SEQL - 1));
  ushort4 w4  = ((const ushort4*)dww)[d];
  float wk[4] = {bf2f(w4.x), bf2f(w4.y), bf2f(w4.z), bf2f(w4.w)};
  float acc   = bf2f(dwb[d]);
#pragma unroll
  for (int k = 0; k < 4; k++) {
    const int ll = l + k - 3;
    if (ll >= 0) acc = fmaf(bf2f(xn[(long)(t + k - 3) * DM + d]), wk[k], acc);
  }
  y[(long)t * DM + d] = f2bf(acc);
}

// ---------------- scan --------------------------------------------------------
__device__ __forceinline__ void cv_compute(float gt, float& c, float& sg) {
  gt = fminf(fmaxf(gt, -40.f), 40.f);
  const float e  = __expf(-fabsf(gt));
  const float r  = 1.f / (1.f + e);
  const float rs = e * r;
  c  = (gt >= 0.f) ? rs : r;   // sigmoid(-gt)
  sg = (gt >= 0.f) ? r : rs;   // sigmoid(gt)
}
__device__ __forceinline__ float gfun(float hid) {
  hid = fminf(fmaxf(hid, -40.f), 40.f);
  if (hid >= 0.f) return hid + 0.5f;
  const float e = __expf(hid);
  return e / (1.f + e);
}

__global__ void scan_p1(const unsigned short* __restrict__ hg, float* __restrict__ cC,
                        float* __restrict__ cV, int chTot, int SL) {
  const int e = threadIdx.x, bh = blockIdx.y, cid = blockIdx.x;
  const int bL = bh >> 2, hh = bh & 3;
  long base = ((long)(bL * SL + cid * CHLEN)) * 3072 + hh * 768 + e;
  float C = 1.f, V = 0.f;
  for (int i = 0; i < CHLEN; i++) {
    const float hid = bf2f(hg[base]), gt = bf2f(hg[base + 384]);
    float c, sg; cv_compute(gt, c, sg);
    C *= c;
    V = fmaf(c, V, sg * gfun(hid));
    base += 3072;
  }
  const int idx = cid * chTot + bh * 384 + e;
  cC[idx] = C; cV[idx] = V;
}

__global__ void scan_p2(const float* __restrict__ cC, const float* __restrict__ cV,
                        float* __restrict__ hin, int chTot, int CHNp,
                        const float* __restrict__ hcarry, int useCarry) {
  const int ch = blockIdx.x * 384 + threadIdx.x;
  float h = useCarry ? hcarry[ch] : 0.f;
  for (int cid = 0; cid < CHNp; cid++) {
    const int idx = cid * chTot + ch;
    hin[idx] = h;
    h = fmaf(cC[idx], h, cV[idx]);
  }
}

__global__ void scan_p3(const unsigned short* __restrict__ hg, const float* __restrict__ hin,
                        unsigned short* __restrict__ hout, void* __restrict__ nh, long nhOff,
                        float* __restrict__ hcarry, int chTot, int SL, int CHNp,
                        int writeNh, const int* __restrict__ flagp) {
  const int e = threadIdx.x, bh = blockIdx.y, cid = blockIdx.x;
  const int bL = bh >> 2, hh = bh & 3;
  const long tok = (long)bL * SL + (long)cid * CHLEN;
  long base  = tok * 3072 + hh * 768 + e;
  long obase = tok * 1536 + hh * 384 + e;
  float h = hin[cid * chTot + bh * 384 + e];
  for (int i = 0; i < CHLEN; i++) {
    const float hid = bf2f(hg[base]), gt = bf2f(hg[base + 384]);
    float c, sg; cv_compute(gt, c, sg);
    h = fmaf(c, h, sg * gfun(hid));
    hout[obase] = f2bf(h);
    base += 3072; obase += 1536;
  }
  if (cid == CHNp - 1) {
    hcarry[bh * 384 + e] = h;
    if (writeNh) stout(nh, nhOff + bL * 1536 + hh * 384 + e, *flagp, h);
  }
}

// ---------------- weight conversion / transposes (flag-branching reads) -------
__global__ void cvt_k(const void* __restrict__ in, unsigned short* __restrict__ out,
                      int n, const int* __restrict__ flagp) {
  const int i = blockIdx.x * 256 + threadIdx.x;
  if (i < n) out[i] = f2bf(ldin(in, i, *flagp));
}
__global__ void tr_whg(const void* __restrict__ in, unsigned short* __restrict__ out,
                       const int* __restrict__ flagp) {
  const int idx = blockIdx.x * 256 + threadIdx.x;  // (h*768+n)*256+k
  const int k = idx & 255, n = (idx >> 8) % 768, h = idx / (768 * 256);
  out[idx] = f2bf(ldin(in, (long)(h * 256 + k) * 768 + n, *flagp));
}
__global__ void tr_wout(const void* __restrict__ in, unsigned short* __restrict__ out,
                        const int* __restrict__ flagp) {
  const int idx = blockIdx.x * 256 + threadIdx.x;  // (h*256+n)*384+k
  const int k = idx % 384, n = (idx / 384) & 255, h = idx / (384 * 256);
  out[idx] = f2bf(ldin(in, (long)(h * 384 + k) * 256 + n, *flagp));
}
__global__ void tr_wg(const void* __restrict__ in, unsigned short* __restrict__ out,
                      const int* __restrict__ flagp) {
  const int idx = blockIdx.x * 256 + threadIdx.x;  // n*1024+k, n<2816
  const int k = idx & 1023, n = idx >> 10;
  out[idx] = (n < FFN) ? f2bf(ldin(in, (long)k * FFN + n, *flagp)) : (unsigned short)0;
}
__global__ void tr_wfo(const void* __restrict__ in, unsigned short* __restrict__ out,
                       const int* __restrict__ flagp) {
  const int idx = blockIdx.x * 256 + threadIdx.x;  // n*2816+kk
  const int kk = idx % FFP, n = idx / FFP;
  out[idx] = (kk < FFN) ? f2bf(ldin(in, (long)kk * DM + n, *flagp)) : (unsigned short)0;
}

// ---------------- launch ------------------------------------------------------
extern "C" void kernel_launch(void* const* d_in, const int* in_sizes, int n_in,
                              void* d_out, int out_size, void* d_ws, size_t ws_size,
                              hipStream_t stream) {
  const void* x      = d_in[0];
  const void* dw_w   = d_in[1];
  const void* dw_b   = d_in[2];
  const void* pw_w   = d_in[3];  // [N=1024][K=1024] already
  const void* pw_b   = d_in[4];
  const void* conv_g = d_in[5];
  const void* gru_g  = d_in[6];
  const void* ff_g   = d_in[7];
  const void* w_hg   = d_in[8];
  const void* w_out  = d_in[9];
  const void* w_gate = d_in[10];
  const void* w_val  = d_in[11];
  const void* w_ffo  = d_in[12];

  // Pass size from ws_size (deterministic): need(MT) = 21,795,072 + MT*13,888.
  const long FIXED = 21795072L;
  int MT = 128;
  if      (ws_size >= (size_t)(FIXED + 16384L * 13888)) MT = 16384;
  else if (ws_size >= (size_t)(FIXED + 8192L * 13888))  MT = 8192;
  else if (ws_size >= (size_t)(FIXED + 4096L * 13888))  MT = 4096;
  else if (ws_size >= (size_t)(FIXED + 2048L * 13888))  MT = 2048;
  else if (ws_size >= (size_t)(FIXED + 1024L * 13888))  MT = 1024;
  else if (ws_size >= (size_t)(FIXED + 512L * 13888))   MT = 512;
  else if (ws_size >= (size_t)(FIXED + 256L * 13888))   MT = 256;

  const int SL    = (MT >= SEQL) ? SEQL : MT;
  const int nSeq  = MT / SL;
  const int CHNp  = SL / CHLEN;
  const int chTot = nSeq * 1536;

  char* p = (char*)d_ws;
  unsigned short* whgT  = (unsigned short*)p; p += 1572864;
  unsigned short* woutT = (unsigned short*)p; p += 786432;
  unsigned short* wgT   = (unsigned short*)p; p += 5767168;
  unsigned short* wvT   = (unsigned short*)p; p += 5767168;
  unsigned short* wfoT  = (unsigned short*)p; p += 5767168;
  unsigned short* pwT   = (unsigned short*)p; p += 2097152;
  unsigned short* dwwB  = (unsigned short*)p; p += 8192;
  unsigned short* dwbB  = (unsigned short*)p; p += 2048;
  unsigned short* pwbB  = (unsigned short*)p; p += 2048;
  unsigned short* cgB   = (unsigned short*)p; p += 2048;
  unsigned short* ggB   = (unsigned short*)p; p += 2048;
  unsigned short* fgB   = (unsigned short*)p; p += 2048;
  int*            flag  = (int*)p;            p += 256;
  float*          hcarry= (float*)p;          p += 12288;
  float*          cC    = (float*)p;          p += (long)MT * 192;
  float*          cV    = (float*)p;          p += (long)MT * 192;
  float*          hin   = (float*)p;          p += (long)MT * 192;
  unsigned short* xnb   = (unsigned short*)p; p += 6144 + (long)MT * 2048;
  unsigned short* xc    = (unsigned short*)p; p += (long)MT * 2048;
  unsigned short* hbuf  = (unsigned short*)p; p += (long)MT * 3072;
  unsigned short* ybuf  = (unsigned short*)p;  // region R: ybuf / hg / ffin
  unsigned short* hg    = (unsigned short*)p;
  unsigned short* ffin  = (unsigned short*)p;
  unsigned short* xn    = xnb + 3 * DM;

  // dtype detection + weight conversion (once per call)
  detect_k<<<1, 256, 0, stream>>>((const unsigned short*)x, flag);
  tr_whg<<<3072, 256, 0, stream>>>(w_hg, whgT, flag);
  tr_wout<<<1536, 256, 0, stream>>>(w_out, woutT, flag);
  tr_wg<<<11264, 256, 0, stream>>>(w_gate, wgT, flag);
  tr_wg<<<11264, 256, 0, stream>>>(w_val, wvT, flag);
  tr_wfo<<<11264, 256, 0, stream>>>(w_ffo, wfoT, flag);
  cvt_k<<<4096, 256, 0, stream>>>(pw_w, pwT, 1048576, flag);
  cvt_k<<<16, 256, 0, stream>>>(dw_w, dwwB, 4096, flag);
  cvt_k<<<4, 256, 0, stream>>>(dw_b, dwbB, 1024, flag);
  cvt_k<<<4, 256, 0, stream>>>(pw_b, pwbB, 1024, flag);
  cvt_k<<<4, 256, 0, stream>>>(conv_g, cgB, 1024, flag);
  cvt_k<<<4, 256, 0, stream>>>(gru_g, ggB, 1024, flag);
  cvt_k<<<4, 256, 0, stream>>>(ff_g, fgB, 1024, flag);

  for (long t0 = 0; t0 < 16384; t0 += MT) {
    const int l0     = (int)(t0 & (SEQL - 1));
    const int P      = (l0 > 0) ? 3 : 0;
    const int seqEnd = (l0 + SL == SEQL);
    const long nhOff = NH_OFF + (t0 / SEQL) * 1536;

    // conv block: xc = pw(dwconv(rmsnorm(x))) + pw_b + x
    rmsnorm_x<<<MT + P, 64, 0, stream>>>(x, (t0 - P) * DM, cgB, xn - (long)P * DM, flag);
    dwconv_k<<<dim3(MT, 4), 256, 0, stream>>>(xn, dwwB, dwbB, ybuf, l0);
    gemm_bf16<1><<<dim3(8, MT / 128, 1), 256, 0, stream>>>(ybuf, DM, 0, pwT, 0, DM,
        xc, DM, 0, 0L, pwbB, x, DM, t0 * DM, flag);

    // GRU block
    rmsnorm_k<<<MT, 64, 0, stream>>>(xc, ggB, xn);
    gemm_bf16<0><<<dim3(6, MT / 128, 4), 256, 0, stream>>>(xn, DM, 256, whgT, 196608, 256,
        hg, 3072, 768, 0L, nullptr, nullptr, 0, 0L, nullptr);
    scan_p1<<<dim3(CHNp, nSeq * 4), 384, 0, stream>>>(hg, cC, cV, chTot, SL);
    scan_p2<<<nSeq * 4, 384, 0, stream>>>(cC, cV, hin, chTot, CHNp, hcarry, l0 > 0);
    scan_p3<<<dim3(CHNp, nSeq * 4), 384, 0, stream>>>(hg, hin, hbuf, d_out, nhOff,
        hcarry, chTot, SL, CHNp, seqEnd, flag);
    gemm_bf16<2><<<dim3(2, MT / 128, 4), 256, 0, stream>>>(hbuf, 1536, 384, woutT, 98304, 384,
        xc, DM, 256, 0L, nullptr, xc, DM, 0L, nullptr);

    // FF block
    rmsnorm_k<<<MT, 64, 0, stream>>>(xc, fgB, xn);
    gemm_ff<<<dim3(22, MT / 128), 256, 0, stream>>>(xn, wgT, wvT, ffin);
    gemm_bf16<3><<<dim3(8, MT / 128, 1), 256, 0, stream>>>(ffin, FFP, 0, wfoT, 0, FFP,
        d_out, DM, 0, t0 * DM, nullptr, xc, DM, 0L, flag);
  }
}